// Round 7
// baseline (512.572 us; speedup 1.0000x reference)
//
#include <hip/hip_runtime.h>
#include <hip/hip_cooperative_groups.h>
#include <math.h>

namespace cg = cooperative_groups;

#define N_NODES   100000
#define N_HEDGES  100000
#define N_INC     1000000
#define IN_DIM    128
#define SHIFT     7
#define BMASK     127
#define NBKT      782        // ceil(100000/128)
#define NBLK      245        // ceil(1e6/4096) incidence chunks == grid size
#define NBLK_PAD  248        // padded column length (avoid pow2 stride)
#define PH1_ITEMS 4096
#define NTHREADS  (NBLK * 256)   // 62720
#define NWAVES    (NBLK * 4)     // 980
#define GCHUNK    103            // ceil(N_NODES / NWAVES)

typedef unsigned int u32;

__device__ __forceinline__ void gather_one(const float* __restrict__ src, float* __restrict__ dst,
                                           const int* __restrict__ off, const int* __restrict__ slot,
                                           float b0, float b1, float b2, int r) {
    int s = off[r], e = off[r + 1];
    float a0 = 0.f, a1 = 0.f, a2 = 0.f;
    for (int j = s; j < e; ++j) {
        float4 v = ((const float4*)src)[slot[j]];
        a0 += v.x; a1 += v.y; a2 += v.z;
    }
    float inv = (e > s) ? 1.0f / (float)(e - s) : 0.f;
    ((float4*)dst)[r] = make_float4(a0 * inv + b0, a1 * inv + b1, a2 * inv + b2, 0.f);
}

extern "C" __global__ void __launch_bounds__(256)
mega_kernel(const float* __restrict__ X, const float* __restrict__ W1,
            const float* __restrict__ b1, const float* __restrict__ W2,
            const float* __restrict__ b2v, const float* __restrict__ ov,
            const float* __restrict__ gu, const int* __restrict__ ei,
            int* __restrict__ ws, float* __restrict__ out)
{
    cg::grid_group grid = cg::this_grid();
    const int blk = blockIdx.x, t = threadIdx.x;
    const int wv = t >> 6, lane = t & 63;
    const int gwave = blk * 4 + wv;          // 0..979
    const int gtid = blk * 256 + t;          // 0..62719

    const int* ei0 = ei;                     // nodes
    const int* ei1 = ei + N_INC;             // hedges

    // ---- workspace layout (int units; Z.. starts 16B aligned) ----
    u32* payload_n = (u32*)ws;                       // 1M
    u32* payload_h = payload_n + N_INC;              // 1M
    int* slot_n    = (int*)(payload_h + N_INC);      // 1M
    int* slot_h    = slot_n + N_INC;                 // 1M
    int* off_n     = slot_h + N_INC;                 // 100004
    int* off_h     = off_n + 100004;                 // 100004
    int* histmat   = off_h + 100004;                 // transposed [2*NBKT][NBLK_PAD]
    int* tot       = histmat + 2 * NBKT * NBLK_PAD;  // 1568
    int* boff_n    = tot + 1568;                     // 784
    int* boff_h    = boff_n + 784;                   // 784
    float* cvec    = (float*)(boff_h + 784);         // 16
    float* Z       = cvec + 16;                      // 4*N_NODES
    float* XeA     = Z + 4 * N_NODES;
    float* XnA     = XeA + 4 * N_HEDGES;
    float* XeB     = XnA + 4 * N_NODES;
    float* XnB     = XeB + 4 * N_HEDGES;             // = H2
    float* hard0   = XnB + 4 * N_NODES;
    float* hard2   = hard0 + N_HEDGES;

    __shared__ float w[IN_DIM * 3];
    __shared__ int hA[NBKT], hB[NBKT];
    __shared__ int ph_hist[4][128], ph_curs[4][128];
    __shared__ int sb[8];

    // ================= S0: W12 (LDS), cvec, bin histograms, Z = X @ W12 =====
    if (t < 128) {
        float a0 = 0.f, a1 = 0.f, a2 = 0.f;
        for (int m = 0; m < 64; ++m) {
            float ww = W1[t * 64 + m];
            a0 += ww * W2[m * 3 + 0];
            a1 += ww * W2[m * 3 + 1];
            a2 += ww * W2[m * 3 + 2];
        }
        w[t * 3 + 0] = a0; w[t * 3 + 1] = a1; w[t * 3 + 2] = a2;
    }
    if (blk == 0 && t < 3) {
        float c = 0.f;
        for (int m = 0; m < 64; ++m) c += b1[m] * W2[m * 3 + t];
        cvec[t] = c;
    }
    for (int i = t; i < NBKT; i += 256) { hA[i] = 0; hB[i] = 0; }
    __syncthreads();
    {
        int base4 = blk * (PH1_ITEMS / 4);
        #pragma unroll
        for (int k = 0; k < 4; ++k) {
            int i4 = base4 + k * 256 + t;
            if (i4 * 4 < N_INC) {
                int4 n4 = ((const int4*)ei0)[i4];
                int4 h4 = ((const int4*)ei1)[i4];
                atomicAdd(&hA[n4.x >> SHIFT], 1); atomicAdd(&hB[h4.x >> SHIFT], 1);
                atomicAdd(&hA[n4.y >> SHIFT], 1); atomicAdd(&hB[h4.y >> SHIFT], 1);
                atomicAdd(&hA[n4.z >> SHIFT], 1); atomicAdd(&hB[h4.z >> SHIFT], 1);
                atomicAdd(&hA[n4.w >> SHIFT], 1); atomicAdd(&hB[h4.w >> SHIFT], 1);
            }
        }
        __syncthreads();
        for (int i = t; i < NBKT; i += 256) {
            histmat[(size_t)i * NBLK_PAD + blk]          = hA[i];
            histmat[(size_t)(NBKT + i) * NBLK_PAD + blk] = hB[i];
        }
        // gemm: contiguous GCHUNK rows per wave, 8-deep ILP
        int r0 = gwave * GCHUNK;
        for (int c = 0; c < GCHUNK; c += 8) {
            float2 xv[8];
            #pragma unroll
            for (int q = 0; q < 8; ++q) {
                int row = r0 + c + q;
                xv[q] = (row < N_NODES) ? ((const float2*)(X + (size_t)row * IN_DIM))[lane]
                                        : make_float2(0.f, 0.f);
            }
            #pragma unroll
            for (int q = 0; q < 8; ++q) {
                int row = r0 + c + q;
                if (row < N_NODES) {
                    int k0 = 2 * lane, k1 = k0 + 1;
                    float a0 = xv[q].x * w[k0 * 3 + 0] + xv[q].y * w[k1 * 3 + 0];
                    float a1 = xv[q].x * w[k0 * 3 + 1] + xv[q].y * w[k1 * 3 + 1];
                    float a2 = xv[q].x * w[k0 * 3 + 2] + xv[q].y * w[k1 * 3 + 2];
                    #pragma unroll
                    for (int off = 32; off > 0; off >>= 1) {
                        a0 += __shfl_xor(a0, off);
                        a1 += __shfl_xor(a1, off);
                        a2 += __shfl_xor(a2, off);
                    }
                    if (lane == 0) {
                        Z[(size_t)row * 4 + 0] = a0;
                        Z[(size_t)row * 4 + 1] = a1;
                        Z[(size_t)row * 4 + 2] = a2;
                        Z[(size_t)row * 4 + 3] = 0.f;
                    }
                }
            }
        }
    }
    grid.sync();

    // ================= S1: scanA — coalesced column scan (transposed) =======
    for (int wid = gwave; wid < 2 * NBKT; wid += NWAVES) {
        int* col = histmat + (size_t)wid * NBLK_PAD;
        int carry = 0;
        #pragma unroll
        for (int r = 0; r < 4; ++r) {
            int idx = r * 64 + lane;
            int v = (idx < NBLK) ? col[idx] : 0;
            int s = v;
            #pragma unroll
            for (int d = 1; d < 64; d <<= 1) {
                int u = __shfl_up(s, d);
                if (lane >= d) s += u;
            }
            int total = __shfl(s, 63);
            if (idx < NBLK) col[idx] = s - v + carry;
            carry += total;
        }
        if (lane == 63) tot[wid] = carry;
    }
    grid.sync();

    // ================= S2: scanB — bucket bases (block 0 only) ==============
    if (blk == 0) {
        for (int dir = 0; dir < 2; ++dir) {
            int* boff = dir ? boff_h : boff_n;
            int* off  = dir ? off_h  : off_n;
            int v[4]; int base = t * 4; int T = 0;
            #pragma unroll
            for (int j = 0; j < 4; ++j) {
                int idx = base + j;
                v[j] = (idx < NBKT) ? tot[dir * NBKT + idx] : 0;
                T += v[j];
            }
            int si = T;
            #pragma unroll
            for (int d = 1; d < 64; d <<= 1) {
                int u = __shfl_up(si, d);
                if (lane >= d) si += u;
            }
            if (lane == 63) sb[wv] = si;
            __syncthreads();
            int wbase = 0;
            for (int p = 0; p < wv; ++p) wbase += sb[p];
            int run = wbase + si - T;   // exclusive base for this thread
            #pragma unroll
            for (int j = 0; j < 4; ++j) {
                int idx = base + j;
                if (idx < NBKT) boff[idx] = run;
                run += v[j];
            }
            if (t == 0) { boff[NBKT] = N_INC; off[N_NODES] = N_INC; }
            __syncthreads();
        }
    }
    grid.sync();

    // ================= S3: place payloads into bucket-grouped order =========
    for (int i = t; i < NBKT; i += 256) { hA[i] = 0; hB[i] = 0; }
    __syncthreads();
    {
        int base4 = blk * (PH1_ITEMS / 4);
        #pragma unroll
        for (int k = 0; k < 4; ++k) {
            int i4 = base4 + k * 256 + t;
            if (i4 * 4 < N_INC) {
                int4 n4 = ((const int4*)ei0)[i4];
                int4 h4 = ((const int4*)ei1)[i4];
                int nn[4] = {n4.x, n4.y, n4.z, n4.w};
                int hv[4] = {h4.x, h4.y, h4.z, h4.w};
                #pragma unroll
                for (int e = 0; e < 4; ++e) {
                    int n = nn[e], h = hv[e];
                    int bn = n >> SHIFT, bh = h >> SHIFT;
                    int rn = atomicAdd(&hA[bn], 1);
                    int rh = atomicAdd(&hB[bh], 1);
                    int pn = histmat[(size_t)bn * NBLK_PAD + blk] + boff_n[bn] + rn;
                    int ph = histmat[(size_t)(NBKT + bh) * NBLK_PAD + blk] + boff_h[bh] + rh;
                    payload_n[pn] = ((u32)(n & BMASK) << 17) | (u32)h;   // dest=node, src=hedge
                    payload_h[ph] = ((u32)(h & BMASK) << 17) | (u32)n;   // dest=hedge, src=node
                }
            }
        }
    }
    grid.sync();

    // ================= S4: phase2 — wave-per-bucket fine sort ===============
    for (int bk = gwave; bk < 2 * NBKT; bk += NWAVES) {
        int dir = (bk >= NBKT) ? 1 : 0;
        int b = bk - dir * NBKT;
        const u32* payload = dir ? payload_h : payload_n;
        const int* boff    = dir ? boff_h    : boff_n;
        int* off  = dir ? off_h  : off_n;
        int* slot = dir ? slot_h : slot_n;
        ph_hist[wv][lane] = 0; ph_hist[wv][64 + lane] = 0;
        int base = boff[b], end = boff[b + 1];
        for (int j = base + lane; j < end; j += 64) atomicAdd(&ph_hist[wv][payload[j] >> 17], 1);
        int h0 = ph_hist[wv][lane], h1 = ph_hist[wv][64 + lane];
        int s0 = h0, s1 = h1;
        #pragma unroll
        for (int d = 1; d < 64; d <<= 1) {
            int u0 = __shfl_up(s0, d), u1 = __shfl_up(s1, d);
            if (lane >= d) { s0 += u0; s1 += u1; }
        }
        int tot0 = __shfl(s0, 63);
        int e0 = s0 - h0, e1 = tot0 + s1 - h1;
        int dest0 = (b << SHIFT) + lane, dest1 = dest0 + 64;
        if (dest0 < N_NODES) off[dest0] = base + e0;
        if (dest1 < N_NODES) off[dest1] = base + e1;
        ph_curs[wv][lane] = e0; ph_curs[wv][64 + lane] = e1;
        for (int j = base + lane; j < end; j += 64) {
            u32 p = payload[j];
            int r = atomicAdd(&ph_curs[wv][p >> 17], 1);
            slot[base + r] = (int)(p & 0x1FFFF);
        }
    }
    grid.sync();

    // ================= S5-S8: four seg-mean gathers =========================
    for (int r = gtid; r < N_HEDGES; r += NTHREADS)
        gather_one(Z, XeA, off_h, slot_h, 0.f, 0.f, 0.f, r);
    grid.sync();
    {
        float c0 = cvec[0], c1 = cvec[1], c2 = cvec[2];
        for (int r = gtid; r < N_NODES; r += NTHREADS)
            gather_one(XeA, XnA, off_n, slot_n, c0, c1, c2, r);
    }
    grid.sync();
    for (int r = gtid; r < N_HEDGES; r += NTHREADS)
        gather_one(XnA, XeB, off_h, slot_h, 0.f, 0.f, 0.f, r);
    grid.sync();
    {
        float c0 = b2v[0], c1 = b2v[1], c2 = b2v[2];
        for (int r = gtid; r < N_NODES; r += NTHREADS)
            gather_one(XeB, XnB, off_n, slot_n, c0, c1, c2, r);
    }
    grid.sync();

    // ================= S9: hedge final (mean/sigmoid/norm/gumbel/argmax) ====
    for (int h = gtid; h < N_HEDGES; h += NTHREADS) {
        int s = off_h[h], e = off_h[h + 1];
        float a0 = 0.f, a1 = 0.f, a2 = 0.f;
        for (int j = s; j < e; ++j) {
            float4 v = ((const float4*)XnB)[slot_h[j]];
            a0 += v.x; a1 += v.y; a2 += v.z;
        }
        float binv = (e > s) ? 1.0f / (float)(e - s) : 0.f;
        float s0 = a0 * binv, s1 = a1 * binv, s2 = a2 * binv;
        float x0 = 1.0f / (1.0f + expf(-s0));
        float x1 = 1.0f / (1.0f + expf(-s1));
        float x2 = 1.0f / (1.0f + expf(-s2));
        float rs = x0 + x1 + x2;
        float rinv = rs != 0.f ? 1.0f / rs : 0.f;
        x0 *= rinv; x1 *= rinv; x2 *= rinv;
        const float EPS = 1e-10f;
        float g0 = -logf(-logf(gu[(size_t)h * 3 + 0] + EPS) + EPS);
        float g1 = -logf(-logf(gu[(size_t)h * 3 + 1] + EPS) + EPS);
        float g2 = -logf(-logf(gu[(size_t)h * 3 + 2] + EPS) + EPS);
        // argmax(softmax(x)) == argmax(x); first-max wins like jnp.argmax
        float v0 = x0 + g0, v1 = x1 + g1, v2 = x2 + g2;
        int am = 0; float vm = v0;
        if (v1 > vm) { am = 1; vm = v1; }
        if (v2 > vm) { am = 2; vm = v2; }
        hard0[h] = (am == 0) ? 1.f : 0.f;
        hard2[h] = (am == 2) ? 1.f : 0.f;
    }
    grid.sync();

    // ================= S10: per-incidence sample + masked edge_index ========
    for (int i4 = gtid; i4 < N_INC / 4; i4 += NTHREADS) {
        int4 n4v = ((const int4*)ei0)[i4];
        int4 h4v = ((const int4*)ei1)[i4];
        int nn[4] = {n4v.x, n4v.y, n4v.z, n4v.w};
        int hh[4] = {h4v.x, h4v.y, h4v.z, h4v.w};
        float smp[4], oi[4], oh[4];
        #pragma unroll
        for (int e = 0; e < 4; ++e) {
            float r = hard0[hh[e]];
            float m = hard2[hh[e]] * (ov[nn[e]] < 0.5f ? 1.f : 0.f);
            float s = fmaxf(r, m);
            smp[e] = s;
            bool keep = s > 0.f;
            oi[e] = keep ? (float)nn[e] : -1.f;
            oh[e] = keep ? (float)hh[e] : -1.f;
        }
        ((float4*)out)[i4] = make_float4(smp[0], smp[1], smp[2], smp[3]);
        ((float4*)(out + N_INC))[i4] = make_float4(oi[0], oi[1], oi[2], oi[3]);
        ((float4*)(out + 2 * (size_t)N_INC))[i4] = make_float4(oh[0], oh[1], oh[2], oh[3]);
    }
}

// ---------------------------------------------------------------------------
extern "C" void kernel_launch(void* const* d_in, const int* in_sizes, int n_in,
                              void* d_out, int out_size, void* d_ws, size_t ws_size,
                              hipStream_t stream) {
    const float* X  = (const float*)d_in[0];
    const float* W1 = (const float*)d_in[1];
    const float* b1 = (const float*)d_in[2];
    const float* W2 = (const float*)d_in[3];
    const float* b2 = (const float*)d_in[4];
    const float* ov = (const float*)d_in[5];
    const float* gu = (const float*)d_in[6];
    const int*   ei = (const int*)d_in[7];
    int* ws = (int*)d_ws;
    float* out = (float*)d_out;

    void* args[10] = {(void*)&X, (void*)&W1, (void*)&b1, (void*)&W2, (void*)&b2,
                      (void*)&ov, (void*)&gu, (void*)&ei, (void*)&ws, (void*)&out};
    hipLaunchCooperativeKernel((const void*)mega_kernel, dim3(NBLK), dim3(256),
                               args, 0, stream);
}

// Round 8
// 193.946 us; speedup vs baseline: 2.6429x; 2.6429x over previous
//
#include <hip/hip_runtime.h>
#include <math.h>

#define N_NODES   100000
#define N_HEDGES  100000
#define N_INC     1000000
#define IN_DIM    128
#define SHIFT     7
#define BMASK     127
#define NBKT      782        // ceil(100000/128)
#define CAP       2048       // padded bucket capacity (max expected ~1500)
#define PH1_ITEMS 4096
#define NBLK      245        // ceil(1e6/4096)
#define GCHUNK    103        // ceil(100000 / (245*4 waves))

typedef unsigned int u32;

// ---------------------------------------------------------------------------
// build: per-chunk LDS histogram -> per-(chunk,bucket) global cursor fetch-add
//        -> payload placement into padded buckets. + W12 (LDS) + Z = X@W12.
__global__ void __launch_bounds__(256)
build_kernel(const int* __restrict__ ei0, const int* __restrict__ ei1,
             const float* __restrict__ X, const float* __restrict__ W1,
             const float* __restrict__ b1, const float* __restrict__ W2,
             int* __restrict__ gcur, u32* __restrict__ payload_n,
             u32* __restrict__ payload_h, float* __restrict__ cvec,
             float* __restrict__ Z)
{
    __shared__ int hA[NBKT], hB[NBKT];
    __shared__ float w[IN_DIM * 3];
    int blk = blockIdx.x, t = threadIdx.x;
    int wv = t >> 6, lane = t & 63;

    if (t < 128) {                               // W12 = W1@W2 into LDS
        float a0 = 0.f, a1 = 0.f, a2 = 0.f;
        for (int m = 0; m < 64; ++m) {
            float ww = W1[t * 64 + m];
            a0 += ww * W2[m * 3 + 0];
            a1 += ww * W2[m * 3 + 1];
            a2 += ww * W2[m * 3 + 2];
        }
        w[t * 3 + 0] = a0; w[t * 3 + 1] = a1; w[t * 3 + 2] = a2;
    }
    if (blk == 0 && t < 3) {                     // cvec = b1@W2 (global, for g2)
        float c = 0.f;
        for (int m = 0; m < 64; ++m) c += b1[m] * W2[m * 3 + t];
        cvec[t] = c;
    }
    for (int i = t; i < NBKT; i += 256) { hA[i] = 0; hB[i] = 0; }
    __syncthreads();

    int base4 = blk * (PH1_ITEMS / 4);
    // pass 1: histogram
    #pragma unroll
    for (int k = 0; k < 4; ++k) {
        int i4 = base4 + k * 256 + t;
        if (i4 * 4 < N_INC) {
            int4 n4 = ((const int4*)ei0)[i4];
            int4 h4 = ((const int4*)ei1)[i4];
            atomicAdd(&hA[n4.x >> SHIFT], 1); atomicAdd(&hB[h4.x >> SHIFT], 1);
            atomicAdd(&hA[n4.y >> SHIFT], 1); atomicAdd(&hB[h4.y >> SHIFT], 1);
            atomicAdd(&hA[n4.z >> SHIFT], 1); atomicAdd(&hB[h4.z >> SHIFT], 1);
            atomicAdd(&hA[n4.w >> SHIFT], 1); atomicAdd(&hB[h4.w >> SHIFT], 1);
        }
    }
    __syncthreads();
    // base exchange: chunk's base inside padded bucket via global fetch-add
    for (int i = t; i < NBKT; i += 256) {
        int c = hA[i];
        if (c) hA[i] = i * CAP + atomicAdd(&gcur[i * 16], c);
        c = hB[i];
        if (c) hB[i] = i * CAP + atomicAdd(&gcur[(NBKT + i) * 16], c);
    }
    __syncthreads();
    // pass 2: place payloads (L2-hot re-read of ei)
    #pragma unroll
    for (int k = 0; k < 4; ++k) {
        int i4 = base4 + k * 256 + t;
        if (i4 * 4 < N_INC) {
            int4 n4 = ((const int4*)ei0)[i4];
            int4 h4 = ((const int4*)ei1)[i4];
            int nn[4] = {n4.x, n4.y, n4.z, n4.w};
            int hv[4] = {h4.x, h4.y, h4.z, h4.w};
            #pragma unroll
            for (int e = 0; e < 4; ++e) {
                int n = nn[e], h = hv[e];
                int pn = atomicAdd(&hA[n >> SHIFT], 1);
                int ph = atomicAdd(&hB[h >> SHIFT], 1);
                payload_n[pn] = ((u32)(n & BMASK) << 17) | (u32)h;   // dest=node, src=hedge
                payload_h[ph] = ((u32)(h & BMASK) << 17) | (u32)n;   // dest=hedge, src=node
            }
        }
    }
    // gemm tail: contiguous GCHUNK rows per wave, 8-deep ILP
    int r0 = (blk * 4 + wv) * GCHUNK;
    for (int c = 0; c < GCHUNK; c += 8) {
        float2 xv[8];
        #pragma unroll
        for (int q = 0; q < 8; ++q) {
            int row = r0 + c + q;
            xv[q] = (row < N_NODES) ? ((const float2*)(X + (size_t)row * IN_DIM))[lane]
                                    : make_float2(0.f, 0.f);
        }
        #pragma unroll
        for (int q = 0; q < 8; ++q) {
            int row = r0 + c + q;
            if (row < N_NODES) {
                int k0 = 2 * lane, k1 = k0 + 1;
                float a0 = xv[q].x * w[k0 * 3 + 0] + xv[q].y * w[k1 * 3 + 0];
                float a1 = xv[q].x * w[k0 * 3 + 1] + xv[q].y * w[k1 * 3 + 1];
                float a2 = xv[q].x * w[k0 * 3 + 2] + xv[q].y * w[k1 * 3 + 2];
                #pragma unroll
                for (int off = 32; off > 0; off >>= 1) {
                    a0 += __shfl_xor(a0, off);
                    a1 += __shfl_xor(a1, off);
                    a2 += __shfl_xor(a2, off);
                }
                if (lane == 0) {
                    Z[(size_t)row * 4 + 0] = a0;
                    Z[(size_t)row * 4 + 1] = a1;
                    Z[(size_t)row * 4 + 2] = a2;
                    Z[(size_t)row * 4 + 3] = 0.f;
                }
            }
        }
    }
}

// ---------------------------------------------------------------------------
// phase2: wave-per-bucket fine sort -> packed off_deg + dest-sorted slots.
__global__ void __launch_bounds__(256)
phase2_kernel(const u32* __restrict__ payload_n, const u32* __restrict__ payload_h,
              const int* __restrict__ gcur,
              u32* __restrict__ od_n, u32* __restrict__ od_h,
              int* __restrict__ slot_n, int* __restrict__ slot_h)
{
    __shared__ int hist[4][128], curs[4][128];
    int t = threadIdx.x;
    int wv = t >> 6, lane = t & 63;
    int bk = blockIdx.x * 4 + wv;                 // 0..1563
    int dir = (bk >= NBKT) ? 1 : 0;
    int b = bk - dir * NBKT;
    const u32* payload = dir ? payload_h : payload_n;
    u32* od   = dir ? od_h   : od_n;
    int* slot = dir ? slot_h : slot_n;
    int tot = gcur[bk * 16];
    int base = b * CAP;

    hist[wv][lane] = 0; hist[wv][64 + lane] = 0;
    __syncthreads();
    for (int j = lane; j < tot; j += 64) atomicAdd(&hist[wv][payload[base + j] >> 17], 1);
    __syncthreads();
    int h0 = hist[wv][lane], h1 = hist[wv][64 + lane];
    int s0 = h0, s1 = h1;
    #pragma unroll
    for (int d = 1; d < 64; d <<= 1) {
        int u0 = __shfl_up(s0, d), u1 = __shfl_up(s1, d);
        if (lane >= d) { s0 += u0; s1 += u1; }
    }
    int tot0 = __shfl(s0, 63);
    int e0 = s0 - h0, e1 = tot0 + s1 - h1;
    int d0 = (b << SHIFT) + lane, d1 = d0 + 64;
    if (d0 < N_NODES) od[d0] = ((u32)(base + e0) << 10) | (u32)h0;
    if (d1 < N_NODES) od[d1] = ((u32)(base + e1) << 10) | (u32)h1;
    curs[wv][lane] = e0; curs[wv][64 + lane] = e1;
    __syncthreads();
    for (int j = lane; j < tot; j += 64) {
        u32 p = payload[base + j];
        int r = atomicAdd(&curs[wv][p >> 17], 1);
        slot[base + r] = (int)(p & 0x1FFFF);
    }
}

// ---------------------------------------------------------------------------
// dst[r] = (1/deg) * sum src[slot[j]] (+addv); off_deg = (start<<10)|deg
__global__ void gather_kernel(const float* __restrict__ src, float* __restrict__ dst,
                              const u32* __restrict__ od, const int* __restrict__ slot,
                              const float* __restrict__ addv, int nrows) {
    int r = blockIdx.x * blockDim.x + threadIdx.x;
    if (r >= nrows) return;
    u32 v = od[r];
    int s = (int)(v >> 10), deg = (int)(v & 1023);
    float a0 = 0.f, a1 = 0.f, a2 = 0.f;
    for (int j = s; j < s + deg; ++j) {
        float4 x = ((const float4*)src)[slot[j]];
        a0 += x.x; a1 += x.y; a2 += x.z;
    }
    float inv = deg > 0 ? 1.0f / (float)deg : 0.f;
    float b0 = 0.f, b1 = 0.f, b2 = 0.f;
    if (addv) { b0 = addv[0]; b1 = addv[1]; b2 = addv[2]; }
    ((float4*)dst)[r] = make_float4(a0 * inv + b0, a1 * inv + b1, a2 * inv + b2, 0.f);
}

// per-hedge: gather-mean of H2 -> sigmoid -> rowsum-normalize -> +gumbel -> argmax
__global__ void hedge_final_kernel(const float* __restrict__ H2,
                                   const u32* __restrict__ od_h, const int* __restrict__ slot_h,
                                   const float* __restrict__ gu, float* __restrict__ hard0,
                                   float* __restrict__ hard2, int n) {
    int h = blockIdx.x * blockDim.x + threadIdx.x;
    if (h >= n) return;
    u32 v = od_h[h];
    int s = (int)(v >> 10), deg = (int)(v & 1023);
    float a0 = 0.f, a1 = 0.f, a2 = 0.f;
    for (int j = s; j < s + deg; ++j) {
        float4 x = ((const float4*)H2)[slot_h[j]];
        a0 += x.x; a1 += x.y; a2 += x.z;
    }
    float binv = deg > 0 ? 1.0f / (float)deg : 0.f;
    float s0 = a0 * binv, s1 = a1 * binv, s2 = a2 * binv;
    float x0 = 1.0f / (1.0f + expf(-s0));
    float x1 = 1.0f / (1.0f + expf(-s1));
    float x2 = 1.0f / (1.0f + expf(-s2));
    float rs = x0 + x1 + x2;
    float rinv = rs != 0.f ? 1.0f / rs : 0.f;
    x0 *= rinv; x1 *= rinv; x2 *= rinv;
    const float EPS = 1e-10f;
    float g0 = -logf(-logf(gu[(size_t)h * 3 + 0] + EPS) + EPS);
    float g1 = -logf(-logf(gu[(size_t)h * 3 + 1] + EPS) + EPS);
    float g2 = -logf(-logf(gu[(size_t)h * 3 + 2] + EPS) + EPS);
    // argmax(softmax(x)) == argmax(x); first-max wins like jnp.argmax
    float v0 = x0 + g0, v1 = x1 + g1, v2 = x2 + g2;
    int am = 0; float vm = v0;
    if (v1 > vm) { am = 1; vm = v1; }
    if (v2 > vm) { am = 2; vm = v2; }
    hard0[h] = (am == 0) ? 1.f : 0.f;
    hard2[h] = (am == 2) ? 1.f : 0.f;
}

// per-incidence: sample + masked edge_index (int4 streams, float4 writes)
__global__ void edge_final_kernel(const float* __restrict__ hard0, const float* __restrict__ hard2,
                                  const float* __restrict__ ov,
                                  const int* __restrict__ ei0, const int* __restrict__ ei1,
                                  float* __restrict__ out, int n4) {
    int i4 = blockIdx.x * blockDim.x + threadIdx.x;
    if (i4 >= n4) return;
    int4 n4v = ((const int4*)ei0)[i4];
    int4 h4v = ((const int4*)ei1)[i4];
    int nn[4] = {n4v.x, n4v.y, n4v.z, n4v.w};
    int hh[4] = {h4v.x, h4v.y, h4v.z, h4v.w};
    float smp[4], oi[4], oh[4];
    #pragma unroll
    for (int e = 0; e < 4; ++e) {
        float r = hard0[hh[e]];
        float m = hard2[hh[e]] * (ov[nn[e]] < 0.5f ? 1.f : 0.f);
        float s = fmaxf(r, m);
        smp[e] = s;
        bool keep = s > 0.f;
        oi[e] = keep ? (float)nn[e] : -1.f;
        oh[e] = keep ? (float)hh[e] : -1.f;
    }
    ((float4*)out)[i4] = make_float4(smp[0], smp[1], smp[2], smp[3]);
    ((float4*)(out + N_INC))[i4] = make_float4(oi[0], oi[1], oi[2], oi[3]);
    ((float4*)(out + 2 * (size_t)N_INC))[i4] = make_float4(oh[0], oh[1], oh[2], oh[3]);
}

// ---------------------------------------------------------------------------
extern "C" void kernel_launch(void* const* d_in, const int* in_sizes, int n_in,
                              void* d_out, int out_size, void* d_ws, size_t ws_size,
                              hipStream_t stream) {
    const float* X  = (const float*)d_in[0];
    const float* W1 = (const float*)d_in[1];
    const float* b1 = (const float*)d_in[2];
    const float* W2 = (const float*)d_in[3];
    const float* b2 = (const float*)d_in[4];
    const float* ov = (const float*)d_in[5];
    const float* gu = (const float*)d_in[6];
    const int*   ei = (const int*)d_in[7];
    const int* ei0 = ei;            // nodes
    const int* ei1 = ei + N_INC;    // hedges

    // ---- workspace layout (int units; every section 16B-aligned) ----
    int* ip = (int*)d_ws;
    int* gcur      = ip;                          // 1564 cursors, line-padded: 25024
    u32* payload_n = (u32*)(gcur + 25024);        // NBKT*CAP = 1601536
    u32* payload_h = payload_n + NBKT * CAP;      // 1601536
    int* slot_n    = (int*)(payload_h + NBKT * CAP); // 1601536
    int* slot_h    = slot_n + NBKT * CAP;         // 1601536
    u32* od_n      = (u32*)(slot_h + NBKT * CAP); // 100096
    u32* od_h      = od_n + 100096;               // 100096
    float* cvec    = (float*)(od_h + 100096);     // 16
    float* Z       = cvec + 16;                   // 400000
    float* XeA     = Z    + 4 * N_NODES;          // 400000
    float* XnA     = XeA  + 4 * N_HEDGES;         // 400000
    float* XeB     = XnA  + 4 * N_NODES;          // 400000
    float* XnB     = XeB  + 4 * N_HEDGES;         // 400000 (= H2)
    float* hard0   = XnB  + 4 * N_NODES;          // 100000
    float* hard2   = hard0 + N_HEDGES;            // 100000

    const int TB = 256;
    int gRow = (N_NODES + TB - 1) / TB;           // 391

    hipMemsetAsync(gcur, 0, 25024 * sizeof(int), stream);

    build_kernel<<<NBLK, 256, 0, stream>>>(ei0, ei1, X, W1, b1, W2,
                                           gcur, payload_n, payload_h, cvec, Z);
    phase2_kernel<<<(2 * NBKT) / 4, 256, 0, stream>>>(payload_n, payload_h, gcur,
                                                      od_n, od_h, slot_n, slot_h);

    // layer 1: Xe = mean_hedge(Z); Xn = mean_node(Xe) + cvec
    gather_kernel<<<gRow, TB, 0, stream>>>(Z,   XeA, od_h, slot_h, nullptr, N_HEDGES);
    gather_kernel<<<gRow, TB, 0, stream>>>(XeA, XnA, od_n, slot_n, cvec,    N_NODES);
    // layer 2: H2 = mean_node(mean_hedge(XnA)) + b2
    gather_kernel<<<gRow, TB, 0, stream>>>(XnA, XeB, od_h, slot_h, nullptr, N_HEDGES);
    gather_kernel<<<gRow, TB, 0, stream>>>(XeB, XnB, od_n, slot_n, b2,      N_NODES);

    // scatter-mean of H2 into hedges fused with sigmoid/normalize/gumbel/argmax
    hedge_final_kernel<<<gRow, TB, 0, stream>>>(XnB, od_h, slot_h, gu, hard0, hard2, N_HEDGES);

    edge_final_kernel<<<(N_INC / 4 + TB - 1) / TB, TB, 0, stream>>>(hard0, hard2, ov, ei0, ei1,
                                                                    (float*)d_out, N_INC / 4);
}

// Round 9
// 160.790 us; speedup vs baseline: 3.1878x; 1.2062x over previous
//
#include <hip/hip_runtime.h>
#include <math.h>

#define N_NODES   100000
#define N_HEDGES  100000
#define N_INC     1000000
#define IN_DIM    128
#define SHIFT     7
#define BMASK     127
#define NBKT      782        // ceil(100000/128)
#define CAP       2048       // padded bucket capacity (max expected ~1500)
#define NBLK      245        // ceil(1e6/4096) incidence chunks
#define BT        1024       // build block threads (16 waves -> 4 waves/SIMD)

typedef unsigned int u32;

// ---------------------------------------------------------------------------
// build: per-chunk LDS histogram -> per-(chunk,bucket) global cursor fetch-add
//        -> payload placement into padded buckets. Block 0 also emits W12/cvec.
__global__ void __launch_bounds__(BT)
build_kernel(const int* __restrict__ ei0, const int* __restrict__ ei1,
             const float* __restrict__ W1, const float* __restrict__ b1,
             const float* __restrict__ W2,
             int* __restrict__ gcur, u32* __restrict__ payload_n,
             u32* __restrict__ payload_h, float* __restrict__ W12,
             float* __restrict__ cvec)
{
    __shared__ int hA[NBKT], hB[NBKT];
    int blk = blockIdx.x, t = threadIdx.x;

    if (blk == 0) {                              // W12 = W1@W2, cvec = b1@W2
        if (t < 128) {
            float a0 = 0.f, a1 = 0.f, a2 = 0.f;
            for (int m = 0; m < 64; ++m) {
                float ww = W1[t * 64 + m];
                a0 += ww * W2[m * 3 + 0];
                a1 += ww * W2[m * 3 + 1];
                a2 += ww * W2[m * 3 + 2];
            }
            W12[t * 3 + 0] = a0; W12[t * 3 + 1] = a1; W12[t * 3 + 2] = a2;
        }
        if (t < 3) {
            float c = 0.f;
            for (int m = 0; m < 64; ++m) c += b1[m] * W2[m * 3 + t];
            cvec[t] = c;
        }
    }
    for (int i = t; i < NBKT; i += BT) { hA[i] = 0; hB[i] = 0; }
    __syncthreads();

    int i4 = blk * BT + t;                       // one int4 per thread per pass
    bool ok = (i4 * 4 < N_INC);
    int4 n4 = ok ? ((const int4*)ei0)[i4] : make_int4(0, 0, 0, 0);
    int4 h4 = ok ? ((const int4*)ei1)[i4] : make_int4(0, 0, 0, 0);
    if (ok) {
        atomicAdd(&hA[n4.x >> SHIFT], 1); atomicAdd(&hB[h4.x >> SHIFT], 1);
        atomicAdd(&hA[n4.y >> SHIFT], 1); atomicAdd(&hB[h4.y >> SHIFT], 1);
        atomicAdd(&hA[n4.z >> SHIFT], 1); atomicAdd(&hB[h4.z >> SHIFT], 1);
        atomicAdd(&hA[n4.w >> SHIFT], 1); atomicAdd(&hB[h4.w >> SHIFT], 1);
    }
    __syncthreads();
    // base exchange: chunk's base inside padded bucket via global fetch-add
    for (int i = t; i < NBKT; i += BT) {
        int c = hA[i];
        if (c) hA[i] = i * CAP + atomicAdd(&gcur[i * 16], c);
        c = hB[i];
        if (c) hB[i] = i * CAP + atomicAdd(&gcur[(NBKT + i) * 16], c);
    }
    __syncthreads();
    // place payloads (ei already in registers)
    if (ok) {
        int nn[4] = {n4.x, n4.y, n4.z, n4.w};
        int hv[4] = {h4.x, h4.y, h4.z, h4.w};
        #pragma unroll
        for (int e = 0; e < 4; ++e) {
            int n = nn[e], h = hv[e];
            int pn = atomicAdd(&hA[n >> SHIFT], 1);
            int ph = atomicAdd(&hB[h >> SHIFT], 1);
            payload_n[pn] = ((u32)(n & BMASK) << 17) | (u32)h;   // dest=node, src=hedge
            payload_h[ph] = ((u32)(h & BMASK) << 17) | (u32)n;   // dest=hedge, src=node
        }
    }
}

// ---------------------------------------------------------------------------
// Z[n][0..2] = X[n][:] @ W12 — one wave per node, float2 per lane
__global__ void gemm_z_kernel(const float* __restrict__ X, const float* __restrict__ W12,
                              float* __restrict__ Z, int n_nodes) {
    __shared__ float w[IN_DIM * 3];
    int tid = threadIdx.x;
    for (int i = tid; i < IN_DIM * 3; i += blockDim.x) w[i] = W12[i];
    __syncthreads();

    int wave = tid >> 6;
    int lane = tid & 63;
    int node = blockIdx.x * 4 + wave;
    if (node >= n_nodes) return;

    float2 x2 = ((const float2*)(X + (size_t)node * IN_DIM))[lane];
    int k0 = 2 * lane, k1 = 2 * lane + 1;
    float a0 = x2.x * w[k0 * 3 + 0] + x2.y * w[k1 * 3 + 0];
    float a1 = x2.x * w[k0 * 3 + 1] + x2.y * w[k1 * 3 + 1];
    float a2 = x2.x * w[k0 * 3 + 2] + x2.y * w[k1 * 3 + 2];

    #pragma unroll
    for (int off = 32; off > 0; off >>= 1) {
        a0 += __shfl_xor(a0, off);
        a1 += __shfl_xor(a1, off);
        a2 += __shfl_xor(a2, off);
    }
    if (lane == 0) {
        Z[(size_t)node * 4 + 0] = a0;
        Z[(size_t)node * 4 + 1] = a1;
        Z[(size_t)node * 4 + 2] = a2;
        Z[(size_t)node * 4 + 3] = 0.f;
    }
}

// ---------------------------------------------------------------------------
// phase2: wave-per-bucket fine sort -> packed off_deg + dest-sorted slots.
__global__ void __launch_bounds__(256)
phase2_kernel(const u32* __restrict__ payload_n, const u32* __restrict__ payload_h,
              const int* __restrict__ gcur,
              u32* __restrict__ od_n, u32* __restrict__ od_h,
              int* __restrict__ slot_n, int* __restrict__ slot_h)
{
    __shared__ int hist[4][128], curs[4][128];
    int t = threadIdx.x;
    int wv = t >> 6, lane = t & 63;
    int bk = blockIdx.x * 4 + wv;                 // 0..1563
    int dir = (bk >= NBKT) ? 1 : 0;
    int b = bk - dir * NBKT;
    const u32* payload = dir ? payload_h : payload_n;
    u32* od   = dir ? od_h   : od_n;
    int* slot = dir ? slot_h : slot_n;
    int tot = gcur[bk * 16];
    int base = b * CAP;

    hist[wv][lane] = 0; hist[wv][64 + lane] = 0;
    __syncthreads();
    for (int j = lane; j < tot; j += 64) atomicAdd(&hist[wv][payload[base + j] >> 17], 1);
    __syncthreads();
    int h0 = hist[wv][lane], h1 = hist[wv][64 + lane];
    int s0 = h0, s1 = h1;
    #pragma unroll
    for (int d = 1; d < 64; d <<= 1) {
        int u0 = __shfl_up(s0, d), u1 = __shfl_up(s1, d);
        if (lane >= d) { s0 += u0; s1 += u1; }
    }
    int tot0 = __shfl(s0, 63);
    int e0 = s0 - h0, e1 = tot0 + s1 - h1;
    int d0 = (b << SHIFT) + lane, d1 = d0 + 64;
    if (d0 < N_NODES) od[d0] = ((u32)(base + e0) << 10) | (u32)h0;
    if (d1 < N_NODES) od[d1] = ((u32)(base + e1) << 10) | (u32)h1;
    curs[wv][lane] = e0; curs[wv][64 + lane] = e1;
    __syncthreads();
    for (int j = lane; j < tot; j += 64) {
        u32 p = payload[base + j];
        int r = atomicAdd(&curs[wv][p >> 17], 1);
        slot[base + r] = (int)(p & 0x1FFFF);
    }
}

// ---------------------------------------------------------------------------
// dst[r] = (1/deg) * sum src[slot[j]] (+addv); off_deg = (start<<10)|deg
__global__ void gather_kernel(const float* __restrict__ src, float* __restrict__ dst,
                              const u32* __restrict__ od, const int* __restrict__ slot,
                              const float* __restrict__ addv, int nrows) {
    int r = blockIdx.x * blockDim.x + threadIdx.x;
    if (r >= nrows) return;
    u32 v = od[r];
    int s = (int)(v >> 10), deg = (int)(v & 1023);
    float a0 = 0.f, a1 = 0.f, a2 = 0.f;
    for (int j = s; j < s + deg; ++j) {
        float4 x = ((const float4*)src)[slot[j]];
        a0 += x.x; a1 += x.y; a2 += x.z;
    }
    float inv = deg > 0 ? 1.0f / (float)deg : 0.f;
    float b0 = 0.f, b1 = 0.f, b2 = 0.f;
    if (addv) { b0 = addv[0]; b1 = addv[1]; b2 = addv[2]; }
    ((float4*)dst)[r] = make_float4(a0 * inv + b0, a1 * inv + b1, a2 * inv + b2, 0.f);
}

// per-hedge: gather-mean of H2 -> sigmoid -> rowsum-normalize -> +gumbel -> argmax
__global__ void hedge_final_kernel(const float* __restrict__ H2,
                                   const u32* __restrict__ od_h, const int* __restrict__ slot_h,
                                   const float* __restrict__ gu, float* __restrict__ hard0,
                                   float* __restrict__ hard2, int n) {
    int h = blockIdx.x * blockDim.x + threadIdx.x;
    if (h >= n) return;
    u32 v = od_h[h];
    int s = (int)(v >> 10), deg = (int)(v & 1023);
    float a0 = 0.f, a1 = 0.f, a2 = 0.f;
    for (int j = s; j < s + deg; ++j) {
        float4 x = ((const float4*)H2)[slot_h[j]];
        a0 += x.x; a1 += x.y; a2 += x.z;
    }
    float binv = deg > 0 ? 1.0f / (float)deg : 0.f;
    float s0 = a0 * binv, s1 = a1 * binv, s2 = a2 * binv;
    float x0 = 1.0f / (1.0f + expf(-s0));
    float x1 = 1.0f / (1.0f + expf(-s1));
    float x2 = 1.0f / (1.0f + expf(-s2));
    float rs = x0 + x1 + x2;
    float rinv = rs != 0.f ? 1.0f / rs : 0.f;
    x0 *= rinv; x1 *= rinv; x2 *= rinv;
    const float EPS = 1e-10f;
    float g0 = -logf(-logf(gu[(size_t)h * 3 + 0] + EPS) + EPS);
    float g1 = -logf(-logf(gu[(size_t)h * 3 + 1] + EPS) + EPS);
    float g2 = -logf(-logf(gu[(size_t)h * 3 + 2] + EPS) + EPS);
    // argmax(softmax(x)) == argmax(x); first-max wins like jnp.argmax
    float v0 = x0 + g0, v1 = x1 + g1, v2 = x2 + g2;
    int am = 0; float vm = v0;
    if (v1 > vm) { am = 1; vm = v1; }
    if (v2 > vm) { am = 2; vm = v2; }
    hard0[h] = (am == 0) ? 1.f : 0.f;
    hard2[h] = (am == 2) ? 1.f : 0.f;
}

// per-incidence: sample + masked edge_index (int4 streams, float4 writes)
__global__ void edge_final_kernel(const float* __restrict__ hard0, const float* __restrict__ hard2,
                                  const float* __restrict__ ov,
                                  const int* __restrict__ ei0, const int* __restrict__ ei1,
                                  float* __restrict__ out, int n4) {
    int i4 = blockIdx.x * blockDim.x + threadIdx.x;
    if (i4 >= n4) return;
    int4 n4v = ((const int4*)ei0)[i4];
    int4 h4v = ((const int4*)ei1)[i4];
    int nn[4] = {n4v.x, n4v.y, n4v.z, n4v.w};
    int hh[4] = {h4v.x, h4v.y, h4v.z, h4v.w};
    float smp[4], oi[4], oh[4];
    #pragma unroll
    for (int e = 0; e < 4; ++e) {
        float r = hard0[hh[e]];
        float m = hard2[hh[e]] * (ov[nn[e]] < 0.5f ? 1.f : 0.f);
        float s = fmaxf(r, m);
        smp[e] = s;
        bool keep = s > 0.f;
        oi[e] = keep ? (float)nn[e] : -1.f;
        oh[e] = keep ? (float)hh[e] : -1.f;
    }
    ((float4*)out)[i4] = make_float4(smp[0], smp[1], smp[2], smp[3]);
    ((float4*)(out + N_INC))[i4] = make_float4(oi[0], oi[1], oi[2], oi[3]);
    ((float4*)(out + 2 * (size_t)N_INC))[i4] = make_float4(oh[0], oh[1], oh[2], oh[3]);
}

// ---------------------------------------------------------------------------
extern "C" void kernel_launch(void* const* d_in, const int* in_sizes, int n_in,
                              void* d_out, int out_size, void* d_ws, size_t ws_size,
                              hipStream_t stream) {
    const float* X  = (const float*)d_in[0];
    const float* W1 = (const float*)d_in[1];
    const float* b1 = (const float*)d_in[2];
    const float* W2 = (const float*)d_in[3];
    const float* b2 = (const float*)d_in[4];
    const float* ov = (const float*)d_in[5];
    const float* gu = (const float*)d_in[6];
    const int*   ei = (const int*)d_in[7];
    const int* ei0 = ei;            // nodes
    const int* ei1 = ei + N_INC;    // hedges

    // ---- workspace layout (int units; every section 16B-aligned) ----
    int* ip = (int*)d_ws;
    int* gcur      = ip;                          // 1564 cursors, line-padded: 25024
    u32* payload_n = (u32*)(gcur + 25024);        // NBKT*CAP = 1601536
    u32* payload_h = payload_n + NBKT * CAP;      // 1601536
    int* slot_n    = (int*)(payload_h + NBKT * CAP); // 1601536
    int* slot_h    = slot_n + NBKT * CAP;         // 1601536
    u32* od_n      = (u32*)(slot_h + NBKT * CAP); // 100096
    u32* od_h      = od_n + 100096;               // 100096
    float* W12     = (float*)(od_h + 100096);     // 384
    float* cvec    = W12 + 384;                   // 16
    float* Z       = cvec + 16;                   // 400000
    float* XeA     = Z    + 4 * N_NODES;          // 400000
    float* XnA     = XeA  + 4 * N_HEDGES;         // 400000
    float* XeB     = XnA  + 4 * N_NODES;          // 400000
    float* XnB     = XeB  + 4 * N_HEDGES;         // 400000 (= H2)
    float* hard0   = XnB  + 4 * N_NODES;          // 100000
    float* hard2   = hard0 + N_HEDGES;            // 100000

    const int TB = 256;
    int gRow = (N_NODES + TB - 1) / TB;           // 391

    hipMemsetAsync(gcur, 0, 25024 * sizeof(int), stream);

    build_kernel<<<NBLK, BT, 0, stream>>>(ei0, ei1, W1, b1, W2,
                                          gcur, payload_n, payload_h, W12, cvec);
    gemm_z_kernel<<<(N_NODES + 3) / 4, 256, 0, stream>>>(X, W12, Z, N_NODES);
    phase2_kernel<<<(2 * NBKT) / 4, 256, 0, stream>>>(payload_n, payload_h, gcur,
                                                      od_n, od_h, slot_n, slot_h);

    // layer 1: Xe = mean_hedge(Z); Xn = mean_node(Xe) + cvec
    gather_kernel<<<gRow, TB, 0, stream>>>(Z,   XeA, od_h, slot_h, nullptr, N_HEDGES);
    gather_kernel<<<gRow, TB, 0, stream>>>(XeA, XnA, od_n, slot_n, cvec,    N_NODES);
    // layer 2: H2 = mean_node(mean_hedge(XnA)) + b2
    gather_kernel<<<gRow, TB, 0, stream>>>(XnA, XeB, od_h, slot_h, nullptr, N_HEDGES);
    gather_kernel<<<gRow, TB, 0, stream>>>(XeB, XnB, od_n, slot_n, b2,      N_NODES);

    // scatter-mean of H2 into hedges fused with sigmoid/normalize/gumbel/argmax
    hedge_final_kernel<<<gRow, TB, 0, stream>>>(XnB, od_h, slot_h, gu, hard0, hard2, N_HEDGES);

    edge_final_kernel<<<(N_INC / 4 + TB - 1) / TB, TB, 0, stream>>>(hard0, hard2, ov, ei0, ei1,
                                                                    (float*)d_out, N_INC / 4);
}

// Round 10
// 128.102 us; speedup vs baseline: 4.0013x; 1.2552x over previous
//
#include <hip/hip_runtime.h>
#include <math.h>

#define N_NODES   100000
#define N_HEDGES  100000
#define N_INC     1000000
#define IN_DIM    128
#define SHIFT     7
#define BMASK     127
#define NBKT      782        // ceil(100000/128)
#define CAP       2048       // padded bucket capacity (max expected ~1500)
#define NBLK      245        // ceil(1e6/4096) incidence chunks
#define BT        1024       // build block threads (16 waves -> 4 waves/SIMD)

typedef unsigned int u32;

// ---------------------------------------------------------------------------
// build: per-chunk LDS histogram -> per-(chunk,bucket) global cursor fetch-add
//        -> payload placement into padded buckets. Block 0 also emits W12/cvec.
__global__ void __launch_bounds__(BT)
build_kernel(const int* __restrict__ ei0, const int* __restrict__ ei1,
             const float* __restrict__ W1, const float* __restrict__ b1,
             const float* __restrict__ W2,
             int* __restrict__ gcur, u32* __restrict__ payload_n,
             u32* __restrict__ payload_h, float* __restrict__ W12,
             float* __restrict__ cvec)
{
    __shared__ int hA[NBKT], hB[NBKT];
    int blk = blockIdx.x, t = threadIdx.x;

    if (blk == 0) {                              // W12 = W1@W2, cvec = b1@W2
        if (t < 128) {
            float a0 = 0.f, a1 = 0.f, a2 = 0.f;
            for (int m = 0; m < 64; ++m) {
                float ww = W1[t * 64 + m];
                a0 += ww * W2[m * 3 + 0];
                a1 += ww * W2[m * 3 + 1];
                a2 += ww * W2[m * 3 + 2];
            }
            W12[t * 3 + 0] = a0; W12[t * 3 + 1] = a1; W12[t * 3 + 2] = a2;
        }
        if (t < 3) {
            float c = 0.f;
            for (int m = 0; m < 64; ++m) c += b1[m] * W2[m * 3 + t];
            cvec[t] = c;
        }
    }
    for (int i = t; i < NBKT; i += BT) { hA[i] = 0; hB[i] = 0; }
    __syncthreads();

    int i4 = blk * BT + t;                       // one int4 per thread per pass
    bool ok = (i4 * 4 < N_INC);
    int4 n4 = ok ? ((const int4*)ei0)[i4] : make_int4(0, 0, 0, 0);
    int4 h4 = ok ? ((const int4*)ei1)[i4] : make_int4(0, 0, 0, 0);
    if (ok) {
        atomicAdd(&hA[n4.x >> SHIFT], 1); atomicAdd(&hB[h4.x >> SHIFT], 1);
        atomicAdd(&hA[n4.y >> SHIFT], 1); atomicAdd(&hB[h4.y >> SHIFT], 1);
        atomicAdd(&hA[n4.z >> SHIFT], 1); atomicAdd(&hB[h4.z >> SHIFT], 1);
        atomicAdd(&hA[n4.w >> SHIFT], 1); atomicAdd(&hB[h4.w >> SHIFT], 1);
    }
    __syncthreads();
    // base exchange: chunk's base inside padded bucket via global fetch-add
    for (int i = t; i < NBKT; i += BT) {
        int c = hA[i];
        if (c) hA[i] = i * CAP + atomicAdd(&gcur[i * 16], c);
        c = hB[i];
        if (c) hB[i] = i * CAP + atomicAdd(&gcur[(NBKT + i) * 16], c);
    }
    __syncthreads();
    // place payloads (ei already in registers)
    if (ok) {
        int nn[4] = {n4.x, n4.y, n4.z, n4.w};
        int hv[4] = {h4.x, h4.y, h4.z, h4.w};
        #pragma unroll
        for (int e = 0; e < 4; ++e) {
            int n = nn[e], h = hv[e];
            int pn = atomicAdd(&hA[n >> SHIFT], 1);
            int ph = atomicAdd(&hB[h >> SHIFT], 1);
            payload_n[pn] = ((u32)(n & BMASK) << 17) | (u32)h;   // dest=node, src=hedge
            payload_h[ph] = ((u32)(h & BMASK) << 17) | (u32)n;   // dest=hedge, src=node
        }
    }
}

// ---------------------------------------------------------------------------
// Z[n][0..2] = X[n][:] @ W12 — 2 nodes per wave, float4 per lane (32 lanes/row)
__global__ void gemm_z_kernel(const float* __restrict__ X, const float* __restrict__ W12,
                              float* __restrict__ Z, int n_nodes) {
    __shared__ float w[IN_DIM * 3];
    int tid = threadIdx.x;
    for (int i = tid; i < IN_DIM * 3; i += blockDim.x) w[i] = W12[i];
    __syncthreads();

    int wave = tid >> 6;
    int lane = tid & 63;
    int half = lane >> 5, l = lane & 31;
    int node = (blockIdx.x * 4 + wave) * 2 + half;
    if (node >= n_nodes) return;

    float4 x4 = ((const float4*)(X + (size_t)node * IN_DIM))[l];
    int k = 4 * l;
    float a0 = x4.x * w[k*3+0] + x4.y * w[(k+1)*3+0] + x4.z * w[(k+2)*3+0] + x4.w * w[(k+3)*3+0];
    float a1 = x4.x * w[k*3+1] + x4.y * w[(k+1)*3+1] + x4.z * w[(k+2)*3+1] + x4.w * w[(k+3)*3+1];
    float a2 = x4.x * w[k*3+2] + x4.y * w[(k+1)*3+2] + x4.z * w[(k+2)*3+2] + x4.w * w[(k+3)*3+2];

    #pragma unroll
    for (int off = 16; off > 0; off >>= 1) {   // stays within 32-lane half
        a0 += __shfl_xor(a0, off);
        a1 += __shfl_xor(a1, off);
        a2 += __shfl_xor(a2, off);
    }
    if (l == 0) {
        Z[(size_t)node * 4 + 0] = a0;
        Z[(size_t)node * 4 + 1] = a1;
        Z[(size_t)node * 4 + 2] = a2;
        Z[(size_t)node * 4 + 3] = 0.f;
    }
}

// ---------------------------------------------------------------------------
// phase2: block-per-bucket (4 waves cooperate) -> packed off_deg + sorted slots.
__global__ void __launch_bounds__(256)
phase2_kernel(const u32* __restrict__ payload_n, const u32* __restrict__ payload_h,
              const int* __restrict__ gcur,
              u32* __restrict__ od_n, u32* __restrict__ od_h,
              int* __restrict__ slot_n, int* __restrict__ slot_h)
{
    __shared__ int hist[128], curs[128];
    int t = threadIdx.x;
    int bk = blockIdx.x;                          // 0..1563
    int dir = (bk >= NBKT) ? 1 : 0;
    int b = bk - dir * NBKT;
    const u32* payload = dir ? payload_h : payload_n;
    u32* od   = dir ? od_h   : od_n;
    int* slot = dir ? slot_h : slot_n;
    int tot = gcur[bk * 16];
    int base = b * CAP;

    if (t < 128) hist[t] = 0;
    __syncthreads();
    for (int j = t; j < tot; j += 256) atomicAdd(&hist[payload[base + j] >> 17], 1);
    __syncthreads();
    if (t < 64) {                                 // wave 0: scan 128 bins
        int lane = t;
        int h0 = hist[lane], h1 = hist[64 + lane];
        int s0 = h0, s1 = h1;
        #pragma unroll
        for (int d = 1; d < 64; d <<= 1) {
            int u0 = __shfl_up(s0, d), u1 = __shfl_up(s1, d);
            if (lane >= d) { s0 += u0; s1 += u1; }
        }
        int tot0 = __shfl(s0, 63);
        int e0 = s0 - h0, e1 = tot0 + s1 - h1;
        int d0 = (b << SHIFT) + lane, d1 = d0 + 64;
        if (d0 < N_NODES) od[d0] = ((u32)(base + e0) << 10) | (u32)h0;
        if (d1 < N_NODES) od[d1] = ((u32)(base + e1) << 10) | (u32)h1;
        curs[lane] = e0; curs[64 + lane] = e1;
    }
    __syncthreads();
    for (int j = t; j < tot; j += 256) {
        u32 p = payload[base + j];
        int r = atomicAdd(&curs[p >> 17], 1);
        slot[base + r] = (int)(p & 0x1FFFF);
    }
}

// ---------------------------------------------------------------------------
// quad-lane gather: 4 lanes per dest row; od = (start<<10)|deg
__global__ void gather_kernel(const float* __restrict__ src, float* __restrict__ dst,
                              const u32* __restrict__ od, const int* __restrict__ slot,
                              const float* __restrict__ addv, int nrows) {
    int tid = blockIdx.x * blockDim.x + threadIdx.x;
    int r = tid >> 2, sub = tid & 3;
    if (r >= nrows) return;
    u32 v = od[r];
    int s = (int)(v >> 10), deg = (int)(v & 1023);
    float a0 = 0.f, a1 = 0.f, a2 = 0.f;
    for (int j = s + sub; j < s + deg; j += 4) {
        float4 x = ((const float4*)src)[slot[j]];
        a0 += x.x; a1 += x.y; a2 += x.z;
    }
    a0 += __shfl_xor(a0, 1); a1 += __shfl_xor(a1, 1); a2 += __shfl_xor(a2, 1);
    a0 += __shfl_xor(a0, 2); a1 += __shfl_xor(a1, 2); a2 += __shfl_xor(a2, 2);
    if (sub == 0) {
        float inv = deg > 0 ? 1.0f / (float)deg : 0.f;
        float b0 = 0.f, b1 = 0.f, b2 = 0.f;
        if (addv) { b0 = addv[0]; b1 = addv[1]; b2 = addv[2]; }
        ((float4*)dst)[r] = make_float4(a0 * inv + b0, a1 * inv + b1, a2 * inv + b2, 0.f);
    }
}

// quad-lane hedge final: gather-mean of H2 -> sigmoid -> normalize -> gumbel -> argmax
__global__ void hedge_final_kernel(const float* __restrict__ H2,
                                   const u32* __restrict__ od_h, const int* __restrict__ slot_h,
                                   const float* __restrict__ gu, float* __restrict__ hard0,
                                   float* __restrict__ hard2, int n) {
    int tid = blockIdx.x * blockDim.x + threadIdx.x;
    int h = tid >> 2, sub = tid & 3;
    if (h >= n) return;
    u32 v = od_h[h];
    int s = (int)(v >> 10), deg = (int)(v & 1023);
    float a0 = 0.f, a1 = 0.f, a2 = 0.f;
    for (int j = s + sub; j < s + deg; j += 4) {
        float4 x = ((const float4*)H2)[slot_h[j]];
        a0 += x.x; a1 += x.y; a2 += x.z;
    }
    a0 += __shfl_xor(a0, 1); a1 += __shfl_xor(a1, 1); a2 += __shfl_xor(a2, 1);
    a0 += __shfl_xor(a0, 2); a1 += __shfl_xor(a1, 2); a2 += __shfl_xor(a2, 2);
    if (sub != 0) return;
    float binv = deg > 0 ? 1.0f / (float)deg : 0.f;
    float s0 = a0 * binv, s1 = a1 * binv, s2 = a2 * binv;
    float x0 = 1.0f / (1.0f + expf(-s0));
    float x1 = 1.0f / (1.0f + expf(-s1));
    float x2 = 1.0f / (1.0f + expf(-s2));
    float rs = x0 + x1 + x2;
    float rinv = rs != 0.f ? 1.0f / rs : 0.f;
    x0 *= rinv; x1 *= rinv; x2 *= rinv;
    const float EPS = 1e-10f;
    float g0 = -logf(-logf(gu[(size_t)h * 3 + 0] + EPS) + EPS);
    float g1 = -logf(-logf(gu[(size_t)h * 3 + 1] + EPS) + EPS);
    float g2 = -logf(-logf(gu[(size_t)h * 3 + 2] + EPS) + EPS);
    // argmax(softmax(x)) == argmax(x); first-max wins like jnp.argmax
    float v0 = x0 + g0, v1 = x1 + g1, v2 = x2 + g2;
    int am = 0; float vm = v0;
    if (v1 > vm) { am = 1; vm = v1; }
    if (v2 > vm) { am = 2; vm = v2; }
    hard0[h] = (am == 0) ? 1.f : 0.f;
    hard2[h] = (am == 2) ? 1.f : 0.f;
}

// per-incidence: sample + masked edge_index (int4 streams, float4 writes)
__global__ void edge_final_kernel(const float* __restrict__ hard0, const float* __restrict__ hard2,
                                  const float* __restrict__ ov,
                                  const int* __restrict__ ei0, const int* __restrict__ ei1,
                                  float* __restrict__ out, int n4) {
    int i4 = blockIdx.x * blockDim.x + threadIdx.x;
    if (i4 >= n4) return;
    int4 n4v = ((const int4*)ei0)[i4];
    int4 h4v = ((const int4*)ei1)[i4];
    int nn[4] = {n4v.x, n4v.y, n4v.z, n4v.w};
    int hh[4] = {h4v.x, h4v.y, h4v.z, h4v.w};
    float smp[4], oi[4], oh[4];
    #pragma unroll
    for (int e = 0; e < 4; ++e) {
        float r = hard0[hh[e]];
        float m = hard2[hh[e]] * (ov[nn[e]] < 0.5f ? 1.f : 0.f);
        float s = fmaxf(r, m);
        smp[e] = s;
        bool keep = s > 0.f;
        oi[e] = keep ? (float)nn[e] : -1.f;
        oh[e] = keep ? (float)hh[e] : -1.f;
    }
    ((float4*)out)[i4] = make_float4(smp[0], smp[1], smp[2], smp[3]);
    ((float4*)(out + N_INC))[i4] = make_float4(oi[0], oi[1], oi[2], oi[3]);
    ((float4*)(out + 2 * (size_t)N_INC))[i4] = make_float4(oh[0], oh[1], oh[2], oh[3]);
}

// ---------------------------------------------------------------------------
extern "C" void kernel_launch(void* const* d_in, const int* in_sizes, int n_in,
                              void* d_out, int out_size, void* d_ws, size_t ws_size,
                              hipStream_t stream) {
    const float* X  = (const float*)d_in[0];
    const float* W1 = (const float*)d_in[1];
    const float* b1 = (const float*)d_in[2];
    const float* W2 = (const float*)d_in[3];
    const float* b2 = (const float*)d_in[4];
    const float* ov = (const float*)d_in[5];
    const float* gu = (const float*)d_in[6];
    const int*   ei = (const int*)d_in[7];
    const int* ei0 = ei;            // nodes
    const int* ei1 = ei + N_INC;    // hedges

    // ---- workspace layout (int units; every section 16B-aligned) ----
    int* ip = (int*)d_ws;
    int* gcur      = ip;                          // 1564 cursors, line-padded: 25024
    u32* payload_n = (u32*)(gcur + 25024);        // NBKT*CAP = 1601536
    u32* payload_h = payload_n + NBKT * CAP;      // 1601536
    int* slot_n    = (int*)(payload_h + NBKT * CAP); // 1601536
    int* slot_h    = slot_n + NBKT * CAP;         // 1601536
    u32* od_n      = (u32*)(slot_h + NBKT * CAP); // 100096
    u32* od_h      = od_n + 100096;               // 100096
    float* W12     = (float*)(od_h + 100096);     // 384
    float* cvec    = W12 + 384;                   // 16
    float* Z       = cvec + 16;                   // 400000
    float* XeA     = Z    + 4 * N_NODES;          // 400000
    float* XnA     = XeA  + 4 * N_HEDGES;         // 400000
    float* XeB     = XnA  + 4 * N_NODES;          // 400000
    float* XnB     = XeB  + 4 * N_HEDGES;         // 400000 (= H2)
    float* hard0   = XnB  + 4 * N_NODES;          // 100000
    float* hard2   = hard0 + N_HEDGES;            // 100000

    const int TB = 256;
    int gQuad = (4 * N_NODES + TB - 1) / TB;      // 1563 (quad-lane row kernels)

    hipMemsetAsync(gcur, 0, 25024 * sizeof(int), stream);

    build_kernel<<<NBLK, BT, 0, stream>>>(ei0, ei1, W1, b1, W2,
                                          gcur, payload_n, payload_h, W12, cvec);
    gemm_z_kernel<<<(N_NODES + 7) / 8, 256, 0, stream>>>(X, W12, Z, N_NODES);
    phase2_kernel<<<2 * NBKT, 256, 0, stream>>>(payload_n, payload_h, gcur,
                                                od_n, od_h, slot_n, slot_h);

    // layer 1: Xe = mean_hedge(Z); Xn = mean_node(Xe) + cvec
    gather_kernel<<<gQuad, TB, 0, stream>>>(Z,   XeA, od_h, slot_h, nullptr, N_HEDGES);
    gather_kernel<<<gQuad, TB, 0, stream>>>(XeA, XnA, od_n, slot_n, cvec,    N_NODES);
    // layer 2: H2 = mean_node(mean_hedge(XnA)) + b2
    gather_kernel<<<gQuad, TB, 0, stream>>>(XnA, XeB, od_h, slot_h, nullptr, N_HEDGES);
    gather_kernel<<<gQuad, TB, 0, stream>>>(XeB, XnB, od_n, slot_n, b2,      N_NODES);

    // scatter-mean of H2 into hedges fused with sigmoid/normalize/gumbel/argmax
    hedge_final_kernel<<<gQuad, TB, 0, stream>>>(XnB, od_h, slot_h, gu, hard0, hard2, N_HEDGES);

    edge_final_kernel<<<(N_INC / 4 + TB - 1) / TB, TB, 0, stream>>>(hard0, hard2, ov, ei0, ei1,
                                                                    (float*)d_out, N_INC / 4);
}